// Round 3
// baseline (3520.019 us; speedup 1.0000x reference)
//
#include <hip/hip_runtime.h>

typedef unsigned short u16;

#define NPAPER  100000
#define NAUTHOR 100000
#define NFIELD  50000
#define FIN     128
#define OUTF    349

#define E_WR 1000000
#define E_RW 1000000
#define E_CI 2000000
#define E_HT 1000000
#define E_RH 1000000
#define E_TOT 6000000

// col-space (edge) offsets, concat order: wr, ci, rh, rw, ht
#define CO_CI 1000000
#define CO_RH 3000000
#define CO_RW 4000000
#define CO_HT 5000000
// deg/node-space offsets
#define DB_WR 0
#define DB_CI 100000
#define DB_RH 200000
#define DB_RW 300000
#define DB_HT 400000
#define NDEG  450000

// CSR bucketing: 512 nodes per bucket.
// BCAP sized for worst-case REGION mean: CI/HT regions have avg deg 20 ->
// 512*20 = 10240 expected records/bucket (Poisson sigma ~101). 16384 = +60 sigma.
// (R2 crashed here: BCAP=8192 < 10240 overflowed into poisoned memory.)
#define BSHIFT 9
#define BMASK  511
#define NBUCK  879          // ceil(450000/512)
#define BCAP   16384

static __device__ __forceinline__ float bf2f(u16 u) {
  union { unsigned int i; float f; } c; c.i = ((unsigned int)u) << 16; return c.f;
}
static __device__ __forceinline__ u16 f2bf(float f) {
  union { float f; unsigned int i; } c; c.f = f;
  unsigned int r = c.i + 0x7fffu + ((c.i >> 16) & 1u);
  return (u16)(r >> 16);
}
static __device__ __forceinline__ short f2bs(float f) {   // fast round (no tie-even)
  union { float f; unsigned int i; } c; c.f = f;
  return (short)((c.i + 0x8000u) >> 16);
}

// ---------------- CSR build: bin pass (counts deg + buckets edges) ----------------
__global__ __launch_bounds__(256) void bin_k(
    const int* __restrict__ wr, const int* __restrict__ rw,
    const int* __restrict__ ci, const int* __restrict__ ht,
    const int* __restrict__ rh, int* __restrict__ bcnt,
    int* __restrict__ deg, unsigned int* __restrict__ bins) {
  int e = blockIdx.x * 256 + threadIdx.x;
  if (e >= E_TOT) return;
  const int* ei; int el, db, E;
  if (e < CO_CI)      { ei = wr; el = e;         db = DB_WR; E = E_WR; }
  else if (e < CO_RH) { ei = ci; el = e - CO_CI; db = DB_CI; E = E_CI; }
  else if (e < CO_RW) { ei = rh; el = e - CO_RH; db = DB_RH; E = E_RH; }
  else if (e < CO_HT) { ei = rw; el = e - CO_RW; db = DB_RW; E = E_RW; }
  else                { ei = ht; el = e - CO_HT; db = DB_HT; E = E_HT; }
  int src  = ei[el];
  int gdst = db + ei[E + el];
  atomicAdd(&deg[gdst], 1);
  int b = gdst >> BSHIFT;
  unsigned int rec = ((unsigned int)src << BSHIFT) | (unsigned int)(gdst & BMASK);
  int pos = atomicAdd(&bcnt[b], 1);
  if (pos < BCAP) bins[(size_t)b * BCAP + pos] = rec;   // guard: never OOB
}

// ---------------- CSR build: per-bucket fill, cursors in LDS ----------------
__global__ __launch_bounds__(256) void fill2_k(
    const int* __restrict__ rowptr, const int* __restrict__ bcnt,
    const unsigned int* __restrict__ bins, int* __restrict__ colall) {
  __shared__ int cur[512];
  int b = blockIdx.x;
  int base = b << BSHIFT;
  for (int i = threadIdx.x; i < 512; i += 256) {
    int g = base + i;
    cur[i] = (g < NDEG) ? rowptr[g] : 0;
  }
  __syncthreads();
  int n = bcnt[b];
  if (n > BCAP) n = BCAP;
  const unsigned int* bp = bins + (size_t)b * BCAP;
  for (int i = threadIdx.x; i < n; i += 256) {
    unsigned int rec = bp[i];
    int pos = atomicAdd(&cur[rec & BMASK], 1);
    colall[pos] = (int)(rec >> BSHIFT);
  }
}

// ---------------- scans ----------------
__global__ void scan1(const int* __restrict__ deg, int* __restrict__ rowptr,
                      int* __restrict__ partials) {
  __shared__ int sh[256];
  int tid = threadIdx.x;
  int base = blockIdx.x * 1024 + tid * 4;
  int v0 = (base + 0 < NDEG) ? deg[base + 0] : 0;
  int v1 = (base + 1 < NDEG) ? deg[base + 1] : 0;
  int v2 = (base + 2 < NDEG) ? deg[base + 2] : 0;
  int v3 = (base + 3 < NDEG) ? deg[base + 3] : 0;
  int s = v0 + v1 + v2 + v3;
  sh[tid] = s; __syncthreads();
  int val = s;
  for (int off = 1; off < 256; off <<= 1) {
    int t = (tid >= off) ? sh[tid - off] : 0;
    __syncthreads();
    val += t; sh[tid] = val;
    __syncthreads();
  }
  int excl = val - s;
  if (base + 0 < NDEG) rowptr[base + 0] = excl;
  if (base + 1 < NDEG) rowptr[base + 1] = excl + v0;
  if (base + 2 < NDEG) rowptr[base + 2] = excl + v0 + v1;
  if (base + 3 < NDEG) rowptr[base + 3] = excl + v0 + v1 + v2;
  if (tid == 255) partials[blockIdx.x] = val;
}

__global__ void scan2(int* partials) {
  __shared__ int sh[512];
  int tid = threadIdx.x;
  int v = (tid < 440) ? partials[tid] : 0;
  sh[tid] = v; __syncthreads();
  int val = v;
  for (int off = 1; off < 512; off <<= 1) {
    int t = (tid >= off) ? sh[tid - off] : 0;
    __syncthreads();
    val += t; sh[tid] = val;
    __syncthreads();
  }
  if (tid < 440) partials[tid] = val - v;
}

__global__ void scan3(int* __restrict__ rowptr, const int* __restrict__ partials) {
  int tid = threadIdx.x;
  int base = blockIdx.x * 1024 + tid * 4;
  int add = partials[blockIdx.x];
#pragma unroll
  for (int j = 0; j < 4; ++j) {
    int idx = base + j;
    if (idx < NDEG) rowptr[idx] += add;
  }
  if (blockIdx.x == 0 && tid == 0) rowptr[NDEG] = E_TOT;
}

// ---------------- weight prep: bf16 transposed BT[n][k] + fused biases ----------------
struct PrepArgs {
  const float *wl1_wr, *wr1_wr, *b1_wr;
  const float *wl1_rw, *wr1_rw, *b1_rw;
  const float *wl1_ci, *wr1_ci, *b1_ci;
  const float *wl1_ht, *wr1_ht, *b1_ht;
  const float *wl1_rh, *wr1_rh, *b1_rh;
  const float *wl2_wr, *wr2_wr, *b2_wr;
  const float *wl2_ci, *wr2_ci, *b2_ci;
  const float *wl2_rh, *wr2_rh, *b2_rh;
  u16 *BTp, *BTa, *BTf, *BT2;
  float *biasP, *biasA, *biasF, *bias2;
};

#define PREP_TOT 164701
__global__ void prep_k(PrepArgs a) {
  int i = blockIdx.x * 256 + threadIdx.x;
  if (i >= PREP_TOT) return;
  if (i < 32768) {                 // BTp [256 n][128 k]: cols [ci | rw | ht | sum(wr1_*)]
    int n = i >> 7, k = i & 127;
    float v;
    if (n < 64)       v = a.wl1_ci[k * 64 + n];
    else if (n < 128) v = a.wl1_rw[k * 64 + (n - 64)];
    else if (n < 192) v = a.wl1_ht[k * 64 + (n - 128)];
    else { int c = n - 192; v = a.wr1_wr[k*64+c] + a.wr1_ci[k*64+c] + a.wr1_rh[k*64+c]; }
    a.BTp[i] = f2bf(v);
  } else if (i < 49152) {          // BTa [128 n][128 k]: [wl1_wr | wr1_rw]
    int j = i - 32768; int n = j >> 7, k = j & 127;
    a.BTa[j] = f2bf((n < 64) ? a.wl1_wr[k*64 + n] : a.wr1_rw[k*64 + (n - 64)]);
  } else if (i < 65536) {          // BTf [128 n][128 k]: [wl1_rh | wr1_ht]
    int j = i - 49152; int n = j >> 7, k = j & 127;
    a.BTf[j] = f2bf((n < 64) ? a.wl1_rh[k*64 + n] : a.wr1_ht[k*64 + (n - 64)]);
  } else if (i < 163840) {         // BT2 [384 n][256 k]: [wl2_wr; wl2_ci; wl2_rh; sum(wr2_*)]
    int j = i - 65536; int n = j >> 8, k = j & 255;
    float v = 0.f;
    if (n < 349) {
      if (k < 64)       v = a.wl2_wr[k * 349 + n];
      else if (k < 128) v = a.wl2_ci[(k - 64) * 349 + n];
      else if (k < 192) v = a.wl2_rh[(k - 128) * 349 + n];
      else { int kk = k - 192; v = a.wr2_wr[kk*349+n] + a.wr2_ci[kk*349+n] + a.wr2_rh[kk*349+n]; }
    }
    a.BT2[j] = f2bf(v);
  } else if (i < 164096) {         // biasP 256
    int c = i - 163840;
    a.biasP[c] = (c < 192) ? 0.f : (a.b1_wr[c-192] + a.b1_ci[c-192] + a.b1_rh[c-192]);
  } else if (i < 164224) {         // biasA 128
    int c = i - 164096;
    a.biasA[c] = (c < 64) ? 0.f : a.b1_rw[c - 64];
  } else if (i < 164352) {         // biasF 128
    int c = i - 164224;
    a.biasF[c] = (c < 64) ? 0.f : a.b1_ht[c - 64];
  } else {                         // bias2 349
    int c = i - 164352;
    a.bias2[c] = a.b2_wr[c] + a.b2_ci[c] + a.b2_rh[c];
  }
}

// ---------------- MFMA bf16 GEMM, no-LDS, 128x128 tile, 4 waves x (32x128) ----------------
typedef __attribute__((ext_vector_type(8))) short bf16x8;
typedef __attribute__((ext_vector_type(4))) float f32x4;

static __device__ __forceinline__ bf16x8 ldfrag(const u16* p) {
  return *(const bf16x8*)p;
}
static __device__ __forceinline__ bf16x8 ldfrag(const float* p) {
  float4 lo = *(const float4*)p;
  float4 hi = *(const float4*)(p + 4);
  bf16x8 r;
  r[0] = f2bs(lo.x); r[1] = f2bs(lo.y); r[2] = f2bs(lo.z); r[3] = f2bs(lo.w);
  r[4] = f2bs(hi.x); r[5] = f2bs(hi.y); r[6] = f2bs(hi.z); r[7] = f2bs(hi.w);
  return r;
}
static __device__ __forceinline__ void stC(float* p, float v) { *p = v; }
static __device__ __forceinline__ void stC(u16* p, float v)   { *p = f2bf(v); }

template <typename AT, typename CT>
__global__ __launch_bounds__(256) void mgemm_k(
    const AT* __restrict__ A, const u16* __restrict__ BT,
    const float* __restrict__ bias, CT* __restrict__ C,
    int M, int N, int K, int ldc) {
  int wave = threadIdx.x >> 6;
  int lane = threadIdx.x & 63;
  int l16 = lane & 15, quad = lane >> 4;
  int row0 = blockIdx.x * 128 + wave * 32;
  int col0 = blockIdx.y * 128;

  f32x4 acc[2][8];
  f32x4 zero = {0.f, 0.f, 0.f, 0.f};
#pragma unroll
  for (int f = 0; f < 2; ++f)
#pragma unroll
    for (int g = 0; g < 8; ++g) acc[f][g] = zero;

  int ra0 = row0 + l16;        // clamp A row reads in-bounds; results store-guarded
  int ra1 = row0 + 16 + l16;
  if (ra0 > M - 1) ra0 = M - 1;
  if (ra1 > M - 1) ra1 = M - 1;
  const AT* ap0 = A + (size_t)ra0 * K + quad * 8;
  const AT* ap1 = A + (size_t)ra1 * K + quad * 8;
  const u16* bp = BT + (size_t)(col0 + l16) * K + quad * 8;

  for (int k0 = 0; k0 < K; k0 += 32) {
    bf16x8 a0 = ldfrag(ap0); ap0 += 32;
    bf16x8 a1 = ldfrag(ap1); ap1 += 32;
    bf16x8 bf[8];
#pragma unroll
    for (int g = 0; g < 8; ++g) bf[g] = ldfrag(bp + (size_t)g * 16 * K);
    bp += 32;
#pragma unroll
    for (int g = 0; g < 8; ++g) {
      acc[0][g] = __builtin_amdgcn_mfma_f32_16x16x32_bf16(a0, bf[g], acc[0][g], 0, 0, 0);
      acc[1][g] = __builtin_amdgcn_mfma_f32_16x16x32_bf16(a1, bf[g], acc[1][g], 0, 0, 0);
    }
  }
#pragma unroll
  for (int f = 0; f < 2; ++f) {
    int r0 = row0 + f * 16 + quad * 4;
#pragma unroll
    for (int g = 0; g < 8; ++g) {
      int col = col0 + g * 16 + l16;
      if (col < N) {
        float bv = bias[col];
#pragma unroll
        for (int r = 0; r < 4; ++r) {
          int row = r0 + r;
          if (row < M) stC(C + (size_t)row * ldc + col, acc[f][g][r] + bv);
        }
      }
    }
  }
}

// ---------------- aggregation: one wave per dst node, lane = feature dim ----------------
__global__ __launch_bounds__(256) void agg_kernel(
    const int* __restrict__ rowptr, const int* __restrict__ colall,
    int n_nodes, int n_types, int combine, int do_relu,
    int rpb0, const u16* __restrict__ s0, int st0, int co0,
    int rpb1, const u16* __restrict__ s1, int st1, int co1,
    int rpb2, const u16* __restrict__ s2, int st2, int co2,
    const u16* __restrict__ selfp, int sst, int sco,
    u16* __restrict__ out, int ost, int oco) {
  int lane = threadIdx.x & 63;
  int node = (int)((blockIdx.x * (unsigned)blockDim.x + threadIdx.x) >> 6);
  if (node >= n_nodes) return;
  float tot = 0.f;
  for (int t = 0; t < n_types; ++t) {
    int rpb = (t == 0) ? rpb0 : ((t == 1) ? rpb1 : rpb2);
    const u16* s = (t == 0) ? s0 : ((t == 1) ? s1 : s2);
    int st = (t == 0) ? st0 : ((t == 1) ? st1 : st2);
    int co = (t == 0) ? co0 : ((t == 1) ? co1 : co2);
    int b = rowptr[rpb + node];
    int e = rowptr[rpb + node + 1];
    float acc = 0.f;
    int i = b;
    for (; i + 4 <= e; i += 4) {
      int c0 = colall[i], c1 = colall[i + 1], c2 = colall[i + 2], c3 = colall[i + 3];
      float f0 = bf2f(s[c0 * st + co + lane]);
      float f1 = bf2f(s[c1 * st + co + lane]);
      float f2 = bf2f(s[c2 * st + co + lane]);
      float f3 = bf2f(s[c3 * st + co + lane]);
      acc += (f0 + f1) + (f2 + f3);
    }
    for (; i < e; ++i) acc += bf2f(s[colall[i] * st + co + lane]);
    float m = acc / fmaxf((float)(e - b), 1.f);
    if (combine) tot += m;
    else out[(size_t)node * ost + oco + t * 64 + lane] = f2bf(m);
  }
  if (combine) {
    if (selfp) tot += bf2f(selfp[(size_t)node * sst + sco + lane]);
    if (do_relu) tot = fmaxf(tot, 0.f);
    out[(size_t)node * ost + oco + lane] = f2bf(tot);
  }
}

// ---------------- host ----------------
extern "C" void kernel_launch(void* const* d_in, const int* in_sizes, int n_in,
                              void* d_out, int out_size, void* d_ws, size_t ws_size,
                              hipStream_t stream) {
  (void)in_sizes; (void)n_in; (void)out_size; (void)ws_size;
  const float* x_paper  = (const float*)d_in[0];
  const float* x_author = (const float*)d_in[1];
  const float* x_field  = (const float*)d_in[2];
  const int* ei_wr = (const int*)d_in[3];
  const int* ei_rw = (const int*)d_in[4];
  const int* ei_ci = (const int*)d_in[5];
  const int* ei_ht = (const int*)d_in[6];
  const int* ei_rh = (const int*)d_in[7];
  float* out = (float*)d_out;

  char* w = (char*)d_ws;
  auto alloc = [&](size_t b) { char* p = w; w += (b + 255) & ~(size_t)255; return p; };
  int* deg      = (int*)alloc((size_t)NDEG * 4);
  int* rowptr   = (int*)alloc((size_t)(NDEG + 1) * 4);
  int* partials = (int*)alloc(2048 * 4);
  int* bcnt     = (int*)alloc(1024 * 4);
  int* colall   = (int*)alloc((size_t)E_TOT * 4);
  // yp cols: [0:64]=ci-proj [64:128]=rw-proj [128:192]=ht-proj [192:256]=self -> p1; later cols 0:192 = L2 means
  u16* yp = (u16*)alloc((size_t)NPAPER * 256 * 2);   // 51.2 MB
  u16* ya = (u16*)alloc((size_t)NAUTHOR * 128 * 2);  // 25.6 MB, contiguous after yp
  u16* yf = (u16*)alloc((size_t)NFIELD * 128 * 2);   // [0:64]=f1, [64:128]=self-proj
  u16* BTp   = (u16*)alloc(32768 * 2);
  u16* BTa   = (u16*)alloc(16384 * 2);
  u16* BTf   = (u16*)alloc(16384 * 2);
  u16* BT2   = (u16*)alloc(98304 * 2);
  float* biasP = (float*)alloc(256 * 4);
  float* biasA = (float*)alloc(128 * 4);
  float* biasF = (float*)alloc(128 * 4);
  float* bias2 = (float*)alloc(352 * 4);
  // bins (57.6 MB) aliases yp+ya (76.8 MB contiguous): dead before first GEMM write
  unsigned int* bins = (unsigned int*)yp;

  hipMemsetAsync(deg, 0, (size_t)NDEG * 4, stream);
  hipMemsetAsync(bcnt, 0, 1024 * 4, stream);
  bin_k<<<(E_TOT + 255) / 256, 256, 0, stream>>>(ei_wr, ei_rw, ei_ci, ei_ht, ei_rh, bcnt, deg, bins);
  scan1<<<440, 256, 0, stream>>>(deg, rowptr, partials);
  scan2<<<1, 512, 0, stream>>>(partials);
  scan3<<<440, 256, 0, stream>>>(rowptr, partials);
  fill2_k<<<NBUCK, 256, 0, stream>>>(rowptr, bcnt, bins, colall);

  PrepArgs pa;
  pa.wl1_wr = (const float*)d_in[8];  pa.wr1_wr = (const float*)d_in[9];  pa.b1_wr = (const float*)d_in[10];
  pa.wl1_rw = (const float*)d_in[11]; pa.wr1_rw = (const float*)d_in[12]; pa.b1_rw = (const float*)d_in[13];
  pa.wl1_ci = (const float*)d_in[14]; pa.wr1_ci = (const float*)d_in[15]; pa.b1_ci = (const float*)d_in[16];
  pa.wl1_ht = (const float*)d_in[17]; pa.wr1_ht = (const float*)d_in[18]; pa.b1_ht = (const float*)d_in[19];
  pa.wl1_rh = (const float*)d_in[20]; pa.wr1_rh = (const float*)d_in[21]; pa.b1_rh = (const float*)d_in[22];
  pa.wl2_wr = (const float*)d_in[23]; pa.wr2_wr = (const float*)d_in[24]; pa.b2_wr = (const float*)d_in[25];
  pa.wl2_ci = (const float*)d_in[26]; pa.wr2_ci = (const float*)d_in[27]; pa.b2_ci = (const float*)d_in[28];
  pa.wl2_rh = (const float*)d_in[29]; pa.wr2_rh = (const float*)d_in[30]; pa.b2_rh = (const float*)d_in[31];
  pa.BTp = BTp; pa.BTa = BTa; pa.BTf = BTf; pa.BT2 = BT2;
  pa.biasP = biasP; pa.biasA = biasA; pa.biasF = biasF; pa.bias2 = bias2;
  prep_k<<<(PREP_TOT + 255) / 256, 256, 0, stream>>>(pa);

  // layer-1 projections (MFMA bf16, fp32 A converted in-flight)
  mgemm_k<float, u16><<<dim3(782, 2), 256, 0, stream>>>(x_paper,  BTp, biasP, yp, NPAPER,  256, FIN, 256);
  mgemm_k<float, u16><<<dim3(782, 1), 256, 0, stream>>>(x_author, BTa, biasA, ya, NAUTHOR, 128, FIN, 128);
  mgemm_k<float, u16><<<dim3(391, 1), 256, 0, stream>>>(x_field,  BTf, biasF, yf, NFIELD,  128, FIN, 128);

  // layer-1 aggregation: p1 -> yp[:,192:256], a1 -> ya[:,0:64], f1 -> yf[:,0:64]
  agg_kernel<<<25000, 256, 0, stream>>>(rowptr, colall, NPAPER, 3, 1, 1,
      DB_WR, ya, 128, 0, DB_CI, yp, 256, 0, DB_RH, yf, 128, 0,
      yp, 256, 192, yp, 256, 192);
  agg_kernel<<<25000, 256, 0, stream>>>(rowptr, colall, NAUTHOR, 1, 1, 1,
      DB_RW, yp, 256, 64, 0, (const u16*)nullptr, 0, 0, 0, (const u16*)nullptr, 0, 0,
      ya, 128, 64, ya, 128, 0);
  agg_kernel<<<12500, 256, 0, stream>>>(rowptr, colall, NFIELD, 1, 1, 1,
      DB_HT, yp, 256, 128, 0, (const u16*)nullptr, 0, 0, 0, (const u16*)nullptr, 0, 0,
      yf, 128, 64, yf, 128, 0);
  // layer-2 aggregation: means into yp[:,0:192] (reads p1 at yp[:,192:256], a1, f1)
  agg_kernel<<<25000, 256, 0, stream>>>(rowptr, colall, NPAPER, 3, 0, 0,
      DB_WR, ya, 128, 0, DB_CI, yp, 256, 192, DB_RH, yf, 128, 0,
      (const u16*)nullptr, 0, 0, yp, 256, 0);

  // final fused GEMM: [m_wr | m_ci | m_rh | p1] @ BT2^T + bias2 -> out
  mgemm_k<u16, float><<<dim3(782, 3), 256, 0, stream>>>(yp, BT2, bias2, out, NPAPER, OUTF, 256, OUTF);
}